// Round 11
// baseline (283.461 us; speedup 1.0000x reference)
//
#include <hip/hip_runtime.h>
#include <hip/hip_cooperative_groups.h>

namespace cg = cooperative_groups;

#define N_NODES 100000
#define N_EDGES 1000000
#define D 64
#define N_TYPES 16

#define NPB 128                                  // nodes per bucket (dst >> 7)
#define NBUCK ((N_NODES + NPB - 1) / NPB)        // 782
#define NBLK 256                                 // edge chunks / coop blocks
#define CHUNK ((N_EDGES + NBLK - 1) / NBLK)      // 3907
#define EPT 8                                    // edges per thread (8*512 >= 3907)
#define NODES_PB ((N_NODES + NBLK - 1) / NBLK)   // 391 nodes per coop block
#define ECAP 2048
#define NCHUNK_MAX (N_TYPES + (N_NODES + 63) / 64)   // 1579 apply blocks

// ---------------- workspace layout (4-byte units) ----------------
#define WS_TBL    0
#define WS_BTOT   (WS_TBL + NBUCK * NBLK)
#define WS_BSTART (WS_BTOT + NBUCK)
#define WS_TTBL   (WS_BSTART + NBUCK + 1)
#define WS_TOFF   (WS_TTBL + N_TYPES * NBLK)
#define WS_NLIST  (WS_TOFF + N_TYPES + 1)
#define WS_EBUF   (WS_NLIST + N_NODES)
#define WS_TOTAL  (WS_EBUF + N_EDGES + 64)

// ---- K0 (cooperative): full edge bucket-sort + node type-sort ----
// Edges live in registers across grid syncs; all scans are LDS/shfl.
__global__ void __launch_bounds__(512)
coop_sort(const int* __restrict__ src, const int* __restrict__ dst,
          const int* __restrict__ ntype2,
          int* __restrict__ tbl, int* __restrict__ btot, int* __restrict__ bstart,
          int* __restrict__ ttbl, int* __restrict__ toff,
          int* __restrict__ nlist, unsigned* __restrict__ ebuf) {
    cg::grid_group grid = cg::this_grid();
    __shared__ int hb[NBUCK];                    // counts -> cursors
    __shared__ int gb[NBUCK];                    // global base - local offset
    __shared__ uint2 stage[CHUNK];               // 31.3 KB
    __shared__ int wpart[8];
    __shared__ int ht[N_TYPES];                  // type hist -> type cursors
    __shared__ int stot[N_TYPES];

    int b = blockIdx.x, tid = threadIdx.x;
    int lane = tid & 63, wv = tid >> 6;

    // ---- P1: load edge chunk to registers; bucket hist; type hist ----
    int beg = b * CHUNK, end = min(beg + CHUNK, N_EDGES);
    int ed[EPT], es[EPT];
#pragma unroll
    for (int j = 0; j < EPT; ++j) {
        int e = beg + tid + j * 512;
        ed[j] = (e < end) ? dst[e] : -1;
        es[j] = (e < end) ? src[e] : 0;
    }
    for (int i = tid; i < NBUCK; i += 512) hb[i] = 0;
    if (tid < N_TYPES) ht[tid] = 0;
    __syncthreads();
#pragma unroll
    for (int j = 0; j < EPT; ++j)
        if (ed[j] >= 0) atomicAdd(&hb[ed[j] >> 7], 1);
    int mynode = b * NODES_PB + tid;
    int myt = -1;
    if (tid < NODES_PB && mynode < N_NODES) {
        myt = ntype2[mynode];
        atomicAdd(&ht[myt], 1);
    }
    __syncthreads();
    for (int i = tid; i < NBUCK; i += 512) tbl[i * NBLK + b] = hb[i];
    if (tid < N_TYPES) ttbl[tid * NBLK + b] = ht[tid];

    grid.sync();

    // ---- P2: wave-per-bucket exclusive scan of tbl columns -> btot ----
    int gw = b * 8 + wv;
    if (gw < NBUCK) {
        int4 v = ((int4*)(tbl + gw * NBLK))[lane];
        int s01 = v.x + v.y;
        int s = s01 + v.z + v.w;
        int incl = s;
        for (int o = 1; o < 64; o <<= 1) {
            int u = __shfl_up(incl, o, 64);
            if (lane >= o) incl += u;
        }
        int excl = incl - s;
        int4 w;
        w.x = excl; w.y = excl + v.x; w.z = excl + s01; w.w = excl + s01 + v.z;
        ((int4*)(tbl + gw * NBLK))[lane] = w;
        if (lane == 63) btot[gw] = incl;
    }

    grid.sync();

    // ---- P3: block 0: scan btot -> bstart; block 1: ttbl prefix + toff ----
    if (b == 0) {
        int i0 = 2 * tid, i1 = i0 + 1;
        int v0 = (i0 < NBUCK) ? btot[i0] : 0;
        int v1 = (i1 < NBUCK) ? btot[i1] : 0;
        int s = v0 + v1;
        int incl = s;
        for (int o = 1; o < 64; o <<= 1) {
            int u = __shfl_up(incl, o, 64);
            if (lane >= o) incl += u;
        }
        if (lane == 63) wpart[wv] = incl;
        __syncthreads();
        if (tid == 0) {
            int r = 0;
            for (int w = 0; w < 8; ++w) { int t2 = wpart[w]; wpart[w] = r; r += t2; }
        }
        __syncthreads();
        int excl = incl - s + wpart[wv];
        if (i0 <= NBUCK) bstart[i0] = excl;
        if (i1 <= NBUCK) bstart[i1] = excl + v0;
    } else if (b == 1) {
        for (int t = wv; t < N_TYPES; t += 8) {
            int4 v = ((int4*)(ttbl + t * NBLK))[lane];
            int s01 = v.x + v.y;
            int s = s01 + v.z + v.w;
            int incl = s;
            for (int o = 1; o < 64; o <<= 1) {
                int u = __shfl_up(incl, o, 64);
                if (lane >= o) incl += u;
            }
            int excl = incl - s;
            int4 w;
            w.x = excl; w.y = excl + v.x; w.z = excl + s01; w.w = excl + s01 + v.z;
            ((int4*)(ttbl + t * NBLK))[lane] = w;
            if (lane == 63) stot[t] = incl;
        }
        __syncthreads();
        if (tid == 0) {
            int r = 0;
            for (int t = 0; t < N_TYPES; ++t) { toff[t] = r; r += stot[t]; }
            toff[N_TYPES] = r;
        }
    }

    grid.sync();

    // ---- P4: place edges (LDS stage sorted, burst copy-out) + nodes ----
    for (int i = tid; i < NBUCK; i += 512) hb[i] = 0;
    __syncthreads();
#pragma unroll
    for (int j = 0; j < EPT; ++j)
        if (ed[j] >= 0) atomicAdd(&hb[ed[j] >> 7], 1);
    __syncthreads();
    int i0 = 2 * tid, i1 = i0 + 1;
    int a0 = (i0 < NBUCK) ? hb[i0] : 0;
    int a1 = (i1 < NBUCK) ? hb[i1] : 0;
    int s = a0 + a1;
    int incl = s;
    for (int o = 1; o < 64; o <<= 1) {
        int u = __shfl_up(incl, o, 64);
        if (lane >= o) incl += u;
    }
    if (lane == 63) wpart[wv] = incl;
    __syncthreads();
    if (tid == 0) {
        int r = 0;
        for (int w = 0; w < 8; ++w) { int t2 = wpart[w]; wpart[w] = r; r += t2; }
    }
    __syncthreads();
    int run = incl - s + wpart[wv];
    if (i0 < NBUCK) {
        gb[i0] = bstart[i0] + tbl[i0 * NBLK + b] - run;
        hb[i0] = run;
    }
    if (i1 < NBUCK) {
        gb[i1] = bstart[i1] + tbl[i1 * NBLK + b] - (run + a0);
        hb[i1] = run + a0;
    }
    __syncthreads();
#pragma unroll
    for (int j = 0; j < EPT; ++j) {
        if (ed[j] >= 0) {
            int pos = atomicAdd(&hb[ed[j] >> 7], 1);   // LDS atomic only
            uint2 v; v.x = (unsigned)ed[j]; v.y = (unsigned)es[j];
            stage[pos] = v;
        }
    }
    if (tid < N_TYPES) ht[tid] = toff[tid] + ttbl[tid * NBLK + b];
    __syncthreads();
    int cnt = end - beg;
    for (int idx = tid; idx < cnt; idx += 512) {
        uint2 v = stage[idx];
        int bk = (int)(v.x >> 7);
        ebuf[gb[bk] + idx] = ((v.x & (NPB - 1)) << 20) | v.y;
    }
    if (myt >= 0) {
        int p = atomicAdd(&ht[myt], 1);              // LDS atomic only
        nlist[p] = mynode;
    }
}

// ---- K1: per-bucket local sort + register gather + fp32 mean -> d_out ----
// (round-8 exact, proven 50 us)
__global__ void __launch_bounds__(512)
bucket_gather(const float* __restrict__ feat,
              const int* __restrict__ bstart, const unsigned* __restrict__ ebuf,
              float* __restrict__ out) {
    __shared__ int hist[NPB];
    __shared__ int offL[NPB];
    __shared__ int curL[NPB];
    __shared__ int sortedL[ECAP];

    int k = blockIdx.x, tid = threadIdx.x;
    for (int i = tid; i < NPB; i += 512) hist[i] = 0;
    __syncthreads();
    int beg = bstart[k];
    int ecnt = bstart[k + 1] - beg;
    if (ecnt > ECAP) ecnt = ECAP;
    for (int i = tid; i < ecnt; i += 512)
        atomicAdd(&hist[ebuf[beg + i] >> 20], 1);
    __syncthreads();
    if (tid == 0) {
        int r = 0;
        for (int n = 0; n < NPB; ++n) { offL[n] = r; curL[n] = r; r += hist[n]; }
    }
    __syncthreads();
    for (int i = tid; i < ecnt; i += 512) {
        unsigned p = ebuf[beg + i];
        int pos = atomicAdd(&curL[p >> 20], 1);
        sortedL[pos] = (int)(p & 0xFFFFFu);
    }
    __syncthreads();

    int wv = tid >> 6, lane = tid & 63;
    int sub = lane >> 5, h = lane & 31;
    const float2* __restrict__ F = (const float2*)feat;
    int node0 = k * NPB;
#pragma unroll
    for (int it = 0; it < 8; ++it) {
        int n = (wv * 8 + it) * 2 + sub;
        int cnt = hist[n], o = offL[n];
        float sx = 0.0f, sy = 0.0f;
        int j = 0;
        for (; j + 4 <= cnt; j += 4) {
            int s0 = sortedL[o + j + 0];
            int s1 = sortedL[o + j + 1];
            int s2 = sortedL[o + j + 2];
            int s3 = sortedL[o + j + 3];
            float2 v0 = F[s0 * 32 + h];
            float2 v1 = F[s1 * 32 + h];
            float2 v2 = F[s2 * 32 + h];
            float2 v3 = F[s3 * 32 + h];
            sx += (v0.x + v1.x) + (v2.x + v3.x);
            sy += (v0.y + v1.y) + (v2.y + v3.y);
        }
        for (; j < cnt; ++j) {
            int s = sortedL[o + j];
            float2 v = F[s * 32 + h];
            sx += v.x; sy += v.y;
        }
        float scale = (cnt > 1) ? (1.0f / (float)cnt) : 1.0f;
        int node = node0 + n;
        if (node < N_NODES) {
            float2 r; r.x = sx * scale; r.y = sy * scale;
            ((float2*)out)[node * 32 + h] = r;
        }
    }
}

// ---- K2: apply — one type per block, 64 nodes/block, W column in VGPRs ----
// (round-7 exact) In-place over d_out.
__global__ void __launch_bounds__(256)
apply_typed(const float* __restrict__ gate_W, const float* __restrict__ gate_b,
            const int* __restrict__ toff, const int* __restrict__ nlist,
            float* __restrict__ out) {
    __shared__ float rowbuf[4][D];
    int b = blockIdx.x;
    int t = 0, c0 = 0, acc = 0; bool found = false;
#pragma unroll
    for (int k = 0; k < N_TYPES; ++k) {
        int cnt = toff[k + 1] - toff[k];
        int nch = (cnt + 63) >> 6;
        if (!found && b < acc + nch) { t = k; c0 = b - acc; found = true; }
        acc += nch;
    }
    if (!found) return;

    int lane = threadIdx.x & 63;
    int wv = threadIdx.x >> 6;
    const float* __restrict__ W = gate_W + t * D * D;
    float wreg[D];
#pragma unroll
    for (int d = 0; d < D; ++d) wreg[d] = W[d * D + lane];
    float bias = gate_b[t * D + lane];

    int beg = toff[t] + c0 * 64;
    int lim = toff[t + 1] - beg; if (lim > 64) lim = 64;

    for (int i = wv; i < lim; i += 4) {
        int node = nlist[beg + i];
        float nv = out[node * D + lane];
        rowbuf[wv][lane] = nv;
        float a0 = bias, a1 = 0.0f, a2 = 0.0f, a3 = 0.0f;
#pragma unroll
        for (int d = 0; d < D; d += 4) {
            float4 av = *(const float4*)&rowbuf[wv][d];
            a0 = fmaf(av.x, wreg[d + 0], a0);
            a1 = fmaf(av.y, wreg[d + 1], a1);
            a2 = fmaf(av.z, wreg[d + 2], a2);
            a3 = fmaf(av.w, wreg[d + 3], a3);
        }
        out[node * D + lane] = (a0 + a1) + (a2 + a3);
    }
}

// ================= fallback (round-1 fp32 atomic path) =================
__global__ void scatter_feat(const float* __restrict__ feat, const int* __restrict__ src,
                             const int* __restrict__ dst, float* __restrict__ accum) {
    long long idx = (long long)blockIdx.x * blockDim.x + threadIdx.x;
    if (idx >= (long long)N_EDGES * D) return;
    int e = (int)(idx >> 6), d = (int)(idx & 63);
    atomicAdd(accum + dst[e] * D + d, feat[src[e] * D + d]);
}
__global__ void scatter_deg(const int* __restrict__ dst, float* __restrict__ deg) {
    int e = blockIdx.x * blockDim.x + threadIdx.x;
    if (e >= N_EDGES) return;
    atomicAdd(deg + dst[e], 1.0f);
}
__global__ void apply_linear(const float* __restrict__ gate_W, const float* __restrict__ gate_b,
                             const int* __restrict__ ntype2, const float* __restrict__ deg,
                             float* __restrict__ out) {
    int node = blockIdx.x * (blockDim.x >> 6) + (threadIdx.x >> 6);
    int lane = threadIdx.x & 63;
    if (node >= N_NODES) return;
    int t = ntype2[node];
    float dv = deg[node]; dv = dv > 1.0f ? dv : 1.0f;
    float nv = out[node * D + lane] / dv;
    const float* W = gate_W + t * D * D;
    float acc = gate_b[t * D + lane];
#pragma unroll 16
    for (int d = 0; d < D; ++d)
        acc = fmaf(__shfl(nv, d, 64), W[d * D + lane], acc);
    out[node * D + lane] = acc;
}
// =======================================================================

extern "C" void kernel_launch(void* const* d_in, const int* in_sizes, int n_in,
                              void* d_out, int out_size, void* d_ws, size_t ws_size,
                              hipStream_t stream) {
    const float* feat   = (const float*)d_in[0];
    const float* gate_W = (const float*)d_in[1];
    const float* gate_b = (const float*)d_in[2];
    const int*   src    = (const int*)d_in[3];
    const int*   dst    = (const int*)d_in[4];
    const int*   ntype2 = (const int*)d_in[5];
    float* out = (float*)d_out;

    if (ws_size >= (size_t)WS_TOTAL * 4) {
        int* ws = (int*)d_ws;
        int* tbl       = ws + WS_TBL;
        int* btot      = ws + WS_BTOT;
        int* bstart    = ws + WS_BSTART;
        int* ttbl      = ws + WS_TTBL;
        int* toff      = ws + WS_TOFF;
        int* nlist     = ws + WS_NLIST;
        unsigned* ebuf = (unsigned*)(ws + WS_EBUF);

        void* args[] = {(void*)&src, (void*)&dst, (void*)&ntype2,
                        (void*)&tbl, (void*)&btot, (void*)&bstart,
                        (void*)&ttbl, (void*)&toff, (void*)&nlist, (void*)&ebuf};
        hipLaunchCooperativeKernel((void*)coop_sort, dim3(NBLK), dim3(512),
                                   args, 0, stream);
        bucket_gather<<<NBUCK, 512, 0, stream>>>(feat, bstart, ebuf, out);
        apply_typed<<<NCHUNK_MAX, 256, 0, stream>>>(gate_W, gate_b, toff, nlist, out);
    } else {
        // fallback: round-1 fp32 atomic path (known-good, ~434 us)
        float* deg = (float*)d_ws;
        hipMemsetAsync(out, 0, sizeof(float) * N_NODES * D, stream);
        hipMemsetAsync(deg, 0, sizeof(float) * N_NODES, stream);
        long long total = (long long)N_EDGES * D;
        scatter_feat<<<(int)((total + 255) / 256), 256, 0, stream>>>(feat, src, dst, out);
        scatter_deg<<<(N_EDGES + 255) / 256, 256, 0, stream>>>(dst, deg);
        apply_linear<<<(N_NODES + 3) / 4, 256, 0, stream>>>(gate_W, gate_b, ntype2, deg, out);
    }
}